// Round 17
// baseline (834.379 us; speedup 1.0000x reference)
//
#include <hip/hip_runtime.h>
#include <hip/hip_fp16.h>
#include <math.h>

#define HDIM 128
#define NSLOT 32    // stats copies to spread atomic contention
#define SEGSZ 6272  // histogram segment size (LDS ints)
#define NSLICE 64   // edge slices for histogram

typedef _Float16 f16x8 __attribute__((ext_vector_type(8)));
typedef float f32x4 __attribute__((ext_vector_type(4)));

// ---------------- degree histograms via LDS segments (no global atomics) ----
__global__ __launch_bounds__(256)
void hist_kernel(const int* __restrict__ src, const int* __restrict__ dst,
                 int* __restrict__ partS, int* __restrict__ partD,
                 int nseg, int N, int E) {
    __shared__ int hS[SEGSZ];
    __shared__ int hD[SEGSZ];
    int tid = threadIdx.x;
    int seg = blockIdx.x % nseg;
    int slice = blockIdx.x / nseg;
    int seg0 = seg * SEGSZ;
    for (int i = tid; i < SEGSZ; i += 256) { hS[i] = 0; hD[i] = 0; }
    __syncthreads();
    int chunk = (E + NSLICE - 1) / NSLICE;
    int e0 = slice * chunk;
    int e1 = min(E, e0 + chunk);
    for (int e = e0 + tid; e < e1; e += 256) {
        int s = src[e] - seg0;
        int d = dst[e] - seg0;
        if ((unsigned)s < SEGSZ) atomicAdd(&hS[s], 1);
        if ((unsigned)d < SEGSZ) atomicAdd(&hD[d], 1);
    }
    __syncthreads();
    for (int i = tid; i < SEGSZ; i += 256) {
        int node = seg0 + i;
        if (node < N) {
            partS[(size_t)slice * N + node] = hS[i];
            partD[(size_t)slice * N + node] = hD[i];
        }
    }
}

// reduce partials -> dinv (fused rsqrt) and degD
__global__ void reduce_kernel(const int* __restrict__ partS, const int* __restrict__ partD,
                              float* __restrict__ dinv, int* __restrict__ degD, int N) {
    int i = blockIdx.x * blockDim.x + threadIdx.x;
    if (i >= N) return;
    int sS = 0, sD = 0;
#pragma unroll 8
    for (int k = 0; k < NSLICE; ++k) {
        sS += partS[(size_t)k * N + i];
        sD += partD[(size_t)k * N + i];
    }
    dinv[i] = sS > 0 ? rsqrtf((float)sS) : 0.f;
    degD[i] = sD;
}

// ---- 3-phase multi-block exclusive scan of degD -> rp[0..N] ----
__global__ void scanp1_kernel(const int* __restrict__ deg, int* __restrict__ bsum, int N) {
    __shared__ int sdata[256];
    int i = blockIdx.x * 256 + threadIdx.x;
    sdata[threadIdx.x] = i < N ? deg[i] : 0;
    __syncthreads();
    for (int off = 128; off > 0; off >>= 1) {
        if (threadIdx.x < off) sdata[threadIdx.x] += sdata[threadIdx.x + off];
        __syncthreads();
    }
    if (threadIdx.x == 0) bsum[blockIdx.x] = sdata[0];
}

__global__ __launch_bounds__(1024)
void scanp2_kernel(int* __restrict__ bsum, int nb) {
    __shared__ int part[1024];
    int tid = threadIdx.x;
    int v = tid < nb ? bsum[tid] : 0;
    part[tid] = v;
    __syncthreads();
    for (int off = 1; off < 1024; off <<= 1) {
        int t = tid >= off ? part[tid - off] : 0;
        __syncthreads();
        part[tid] += t;
        __syncthreads();
    }
    if (tid < nb) bsum[tid] = part[tid] - v;   // exclusive
}

__global__ void scanp3_kernel(const int* __restrict__ deg, const int* __restrict__ bsum,
                              int* __restrict__ rp, int N, int E) {
    __shared__ int part[256];
    int tid = threadIdx.x;
    int i = blockIdx.x * 256 + tid;
    int v = i < N ? deg[i] : 0;
    part[tid] = v;
    __syncthreads();
    for (int off = 1; off < 256; off <<= 1) {
        int t = tid >= off ? part[tid - off] : 0;
        __syncthreads();
        part[tid] += t;
        __syncthreads();
    }
    if (i < N) rp[i] = bsum[blockIdx.x] + part[tid] - v;
    if (i == 0) rp[N] = E;
}

__global__ void scatter_kernel(const int* __restrict__ src, const int* __restrict__ dst,
                               const float* __restrict__ dinv, const int* __restrict__ rp,
                               int* __restrict__ cursor, int2* __restrict__ ev, int E) {
    int e = blockIdx.x * blockDim.x + threadIdx.x;
    if (e >= E) return;
    int s = src[e], d = dst[e];
    float w = -dinv[s] * dinv[d];
    int pos = atomicAdd(&cursor[d], 1);
    ev[rp[d] + pos] = make_int2(s, __float_as_int(w));
}

// ---- degree-ordered node permutation (counting sort, 256 bins) ----
__global__ void bcnt_kernel(const int* __restrict__ degD, int* __restrict__ bcnt, int N) {
    __shared__ int h[256];
    int tid = threadIdx.x;
    h[tid] = 0;
    __syncthreads();
    int i = blockIdx.x * 256 + tid;
    if (i < N) { int d = min(degD[i], 255); atomicAdd(&h[d], 1); }
    __syncthreads();
    bcnt[blockIdx.x * 256 + tid] = h[tid];
}

__global__ __launch_bounds__(256)
void bscan_kernel(const int* __restrict__ bcnt, int* __restrict__ boff, int nsl) {
    __shared__ int part[256];
    int b = threadIdx.x;
    int run = 0;
    for (int s = 0; s < nsl; ++s) { boff[s * 256 + b] = run; run += bcnt[s * 256 + b]; }
    part[b] = run;
    __syncthreads();
    for (int off = 1; off < 256; off <<= 1) {
        int t = b >= off ? part[b - off] : 0;
        __syncthreads();
        part[b] += t;
        __syncthreads();
    }
    int base = part[b] - run;   // exclusive over bins
    for (int s = 0; s < nsl; ++s) boff[s * 256 + b] += base;
}

__global__ void bscat_kernel(const int* __restrict__ degD, const int* __restrict__ boff,
                             int* __restrict__ perm, int N) {
    __shared__ int cur[256];
    int tid = threadIdx.x;
    cur[tid] = boff[blockIdx.x * 256 + tid];
    __syncthreads();
    int i = blockIdx.x * 256 + tid;
    if (i < N) {
        int d = min(degD[i], 255);
        int p = atomicAdd(&cur[d], 1);
        perm[p] = i;
    }
}

// ---------------- pure pull: out = L * g(t), degree-ordered nodes -----------
template <int GBN>
__global__ __launch_bounds__(256)
void pull128(const __half* __restrict__ t, const int* __restrict__ rp,
             const int2* __restrict__ ev, const int* __restrict__ perm,
             const float* __restrict__ bnp, __half* __restrict__ outp, int N) {
    int idx = blockIdx.x * 4 + (threadIdx.x >> 6);
    if (idx >= N) return;
    int node = perm[idx];
    int lane = threadIdx.x & 63;
    int c8 = (lane & 15) * 8;     // 8-channel group
    int slot = lane >> 4;         // edge slot 0..3
    const _Float16* tp = (const _Float16*)t;

    float scv[8], shv[8];
    if (GBN) {
#pragma unroll
        for (int i = 0; i < 8; ++i) { scv[i] = bnp[c8 + i]; shv[i] = bnp[128 + c8 + i]; }
    }

    int b = rp[node], e = rp[node + 1];
    float acc0[8] = {}, acc1[8] = {};
    int j = b;
    for (; j + 8 <= e; j += 8) {
        int2 s0 = ev[j + slot];
        int2 s1 = ev[j + 4 + slot];
        f16x8 r0 = *(const f16x8*)(tp + (size_t)s0.x * HDIM + c8);
        f16x8 r1 = *(const f16x8*)(tp + (size_t)s1.x * HDIM + c8);
        float w0 = __int_as_float(s0.y), w1 = __int_as_float(s1.y);
#pragma unroll
        for (int i = 0; i < 8; ++i) {
            float v0 = (float)r0[i], v1 = (float)r1[i];
            if (GBN) { v0 = v0 * scv[i] + shv[i]; v1 = v1 * scv[i] + shv[i]; }
            acc0[i] += w0 * v0; acc1[i] += w1 * v1;
        }
    }
    for (; j < e; j += 4) {
        int idx2 = j + slot;
        if (idx2 < e) {
            int2 s0 = ev[idx2];
            f16x8 r0 = *(const f16x8*)(tp + (size_t)s0.x * HDIM + c8);
            float w0 = __int_as_float(s0.y);
#pragma unroll
            for (int i = 0; i < 8; ++i) {
                float v0 = (float)r0[i];
                if (GBN) v0 = v0 * scv[i] + shv[i];
                acc0[i] += w0 * v0;
            }
        }
    }
    float s[8];
#pragma unroll
    for (int i = 0; i < 8; ++i) {
        s[i] = acc0[i] + acc1[i];
        s[i] += __shfl_xor(s[i], 16);
        s[i] += __shfl_xor(s[i], 32);
    }
    if (lane < 16) {
        size_t o = (size_t)node * HDIM + c8;
        f16x8 h;
#pragma unroll
        for (int i = 0; i < 8; ++i) h[i] = (_Float16)s[i];
        *(f16x8*)((_Float16*)outp + o) = h;
    }
}

__global__ void pull3(const float* __restrict__ t, const float* __restrict__ prev,
                      const int* __restrict__ rp, const int2* __restrict__ ev,
                      float* __restrict__ outp, float alpha, int N) {
    int node = blockIdx.x * blockDim.x + threadIdx.x;
    if (node >= N) return;
    int b = rp[node], e = rp[node + 1];
    float a0 = 0.f, a1 = 0.f, a2 = 0.f;
    for (int j = b; j < e; ++j) {
        int2 sw = ev[j];
        float w = __int_as_float(sw.y);
        const float* r = t + (size_t)sw.x * 3;
        a0 += w * r[0]; a1 += w * r[1]; a2 += w * r[2];
    }
    float r0 = alpha * a0, r1 = alpha * a1, r2 = alpha * a2;
    if (prev) {
        r0 -= prev[node * 3 + 0];
        r1 -= prev[node * 3 + 1];
        r2 -= prev[node * 3 + 2];
    }
    outp[node * 3 + 0] = r0;
    outp[node * 3 + 1] = r1;
    outp[node * 3 + 2] = r2;
}

// ---------------- weight prep: Chebyshev-fold + BN-fold, k-chunk-major fp16 -
__global__ void wprep_kernel(const float* __restrict__ W, const float* __restrict__ bnp,
                             _Float16* __restrict__ Wt) {
    int idx = blockIdx.x * 256 + threadIdx.x;   // 65536 = n(128) x k(512)
    int n = idx >> 9, k = idx & 511;
    int sel = k >> 7, kk = k & 127;
    int o = kk * 128 + n;
    float v;
    if (sel == 0)      v = (W[o] - W[2 * 16384 + o]) * bnp[kk];
    else if (sel == 1) v = W[16384 + o] - 3.f * W[3 * 16384 + o];
    else if (sel == 2) v = 2.f * W[2 * 16384 + o];
    else               v = 4.f * W[3 * 16384 + o];
    Wt[(size_t)((k >> 3) * 128 + n) * 8 + (k & 7)] = (_Float16)v;
}

// bias2[n] = b[n] + sum_k bnp_shift[k] * (W0[k][n] - W2[k][n])
__global__ void bias2_kernel(const float* __restrict__ W, const float* __restrict__ bnp,
                             const float* __restrict__ b, float* __restrict__ bias2) {
    int n = threadIdx.x;
    float s = b[n];
    for (int k = 0; k < 128; ++k)
        s += bnp[128 + k] * (W[k * 128 + n] - W[2 * 16384 + k * 128 + n]);
    bias2[n] = s;
}

// ---------------- MFMA Cheb GEMM with LDS-staged A (no stats) ---------------
template <int ACT, int OUTH>
__global__ __launch_bounds__(256)
void gemm_mfma(const __half* __restrict__ T0, const __half* __restrict__ T1,
               const __half* __restrict__ T2, const __half* __restrict__ T3,
               const _Float16* __restrict__ Wt, const float* __restrict__ bias2,
               __half* __restrict__ outh, float* __restrict__ outf, int N) {
    __shared__ __align__(16) _Float16 As[4][32][136];
    int tid = threadIdx.x;
    int wave = tid >> 6, lane = tid & 63;
    int row0 = blockIdx.x * 32;

    // ---- stage A: wave w loads table w (32 rows x 128 ch fp16 = 8 KB) ----
    {
        const __half* Ts[4] = {T0, T1, T2, T3};
        const _Float16* Tp = (const _Float16*)Ts[wave];
        int lr = lane >> 4;           // row-sub 0..3
        int ko = (lane & 15) * 8;     // k offset (halves)
        f16x8 v[8];
#pragma unroll
        for (int t = 0; t < 8; ++t) {
            int gr = min(row0 + t * 4 + lr, N - 1);
            v[t] = *(const f16x8*)(Tp + (size_t)gr * HDIM + ko);
        }
#pragma unroll
        for (int t = 0; t < 8; ++t)
            *(f16x8*)&As[wave][t * 4 + lr][ko] = v[t];
    }
    __syncthreads();

    int wr = wave >> 1, wc = wave & 1;
    int m = lane & 15, quad = lane >> 4;
    int nbase = wc * 64 + m;

    f32x4 acc[4];
#pragma unroll
    for (int ct = 0; ct < 4; ++ct) acc[ct] = (f32x4){0.f, 0.f, 0.f, 0.f};

#pragma unroll
    for (int kt = 0; kt < 4; ++kt) {
#pragma unroll
        for (int sel = 0; sel < 4; ++sel) {
            f16x8 a = *(const f16x8*)&As[sel][wr * 16 + m][kt * 32 + quad * 8];
            int c0 = sel * 16 + kt * 4 + quad;        // k-chunk index
#pragma unroll
            for (int ct = 0; ct < 4; ++ct) {
                f16x8 b0 = *(const f16x8*)(Wt + ((size_t)c0 * 128 + nbase + ct * 16) * 8);
                acc[ct] = __builtin_amdgcn_mfma_f32_16x16x32_f16(a, b0, acc[ct], 0, 0, 0);
            }
        }
    }

    // epilogue
#pragma unroll
    for (int ct = 0; ct < 4; ++ct) {
        int col = wc * 64 + ct * 16 + m;
        float bv = bias2[col];
#pragma unroll
        for (int r = 0; r < 4; ++r) {
            int drow = row0 + wr * 16 + quad * 4 + r;
            if (drow < N) {
                float v = acc[ct][r] + bv;
                if (ACT == 1) v = v >= 0.f ? v : 0.01f * v;
                else if (ACT == 2) v = fmaxf(v, 0.f);
                if (OUTH) outh[(size_t)drow * HDIM + col] = __float2half(v);
                else      outf[(size_t)drow * HDIM + col] = v;
            }
        }
    }
}

// ---------------- BN stats over fp16 Z (grid-stride streaming) --------------
__global__ __launch_bounds__(256)
void bnstats_kernel(const __half* __restrict__ Z, float* __restrict__ stats, int N) {
    __shared__ float s_sum[128];
    __shared__ float s_sq[128];
    int tid = threadIdx.x;
    int c = tid & 127;
    if (tid < 128) { s_sum[tid] = 0.f; s_sq[tid] = 0.f; }
    __syncthreads();
    float ls = 0.f, lq = 0.f;
    for (int row = blockIdx.x * 2 + (tid >> 7); row < N; row += gridDim.x * 2) {
        float v = __half2float(Z[(size_t)row * HDIM + c]);
        ls += v; lq += v * v;
    }
    atomicAdd(&s_sum[c], ls);
    atomicAdd(&s_sq[c], lq);
    __syncthreads();
    if (tid < 128) {
        float* sp = stats + (size_t)(blockIdx.x & (NSLOT - 1)) * 256;
        atomicAdd(&sp[tid], s_sum[tid]);
        atomicAdd(&sp[128 + tid], s_sq[tid]);
    }
}

// ---------------- layer-1 (input dim 3) fused GEMM, grid-stride ------------
__global__ __launch_bounds__(256)
void gemm1_kernel(const float* __restrict__ x, const float* __restrict__ t1,
                  const float* __restrict__ t2, const float* __restrict__ t3,
                  const float* __restrict__ W1, const float* __restrict__ b1,
                  __half* __restrict__ out, float* __restrict__ stats, int N) {
    __shared__ float s_sum[128];
    __shared__ float s_sq[128];
    int tid = threadIdx.x;
    int c = tid & 127;
    if (tid < 128) { s_sum[tid] = 0.f; s_sq[tid] = 0.f; }
    __syncthreads();
    float wreg[12];
#pragma unroll
    for (int i = 0; i < 12; ++i) wreg[i] = W1[i * 128 + c];
    float bias = b1[c];
    const float* Ts[4] = {x, t1, t2, t3};
    float lsum = 0.f, lsq = 0.f;
    for (int row = blockIdx.x * 2 + (tid >> 7); row < N; row += gridDim.x * 2) {
        float v = bias;
#pragma unroll
        for (int k = 0; k < 4; ++k) {
            const float* t = Ts[k];
#pragma unroll
            for (int d = 0; d < 3; ++d)
                v += t[row * 3 + d] * wreg[k * 3 + d];
        }
        v = v >= 0.f ? v : 0.01f * v;   // leaky_relu
        out[(size_t)row * HDIM + c] = __float2half(v);
        lsum += v; lsq += v * v;
    }
    atomicAdd(&s_sum[c], lsum);
    atomicAdd(&s_sq[c], lsq);
    __syncthreads();
    if (tid < 128) {
        float* sp = stats + (size_t)(blockIdx.x & (NSLOT - 1)) * 256;
        atomicAdd(&sp[tid], s_sum[tid]);
        atomicAdd(&sp[128 + tid], s_sq[tid]);
    }
}

// ---------------- BN finalize: reduce NSLOT stats copies -> (scale, shift) --
__global__ void bnfin_kernel(const float* __restrict__ stats, const float* __restrict__ g,
                             const float* __restrict__ be, float* __restrict__ bnp, float invN) {
    int c = threadIdx.x;  // 128 threads
    float s0 = 0.f, s1 = 0.f;
#pragma unroll 4
    for (int k = 0; k < NSLOT; ++k) {
        s0 += stats[k * 256 + c];
        s1 += stats[k * 256 + 128 + c];
    }
    float m = s0 * invN;
    float v = s1 * invN - m * m;
    float sc = g[c] * rsqrtf(v + 1e-5f);
    bnp[c] = sc;
    bnp[128 + c] = be[c] - m * sc;
}

// ---------------- final: L2-normalize row + project to 3 ----------------
__global__ void final_kernel(const float* __restrict__ Z, const float* __restrict__ Wm,
                             const float* __restrict__ bm, float* __restrict__ out, int N) {
    int gid = blockIdx.x * blockDim.x + threadIdx.x;
    int node = gid >> 6;
    int lane = threadIdx.x & 63;
    if (node >= N) return;
    const float* z = Z + (size_t)node * HDIM;
    float z0 = z[lane], z1 = z[lane + 64];
    float sq = z0 * z0 + z1 * z1;
    float d0 = z0 * Wm[lane * 3 + 0] + z1 * Wm[(lane + 64) * 3 + 0];
    float d1 = z0 * Wm[lane * 3 + 1] + z1 * Wm[(lane + 64) * 3 + 1];
    float d2 = z0 * Wm[lane * 3 + 2] + z1 * Wm[(lane + 64) * 3 + 2];
#pragma unroll
    for (int off = 32; off > 0; off >>= 1) {
        sq += __shfl_down(sq, off);
        d0 += __shfl_down(d0, off);
        d1 += __shfl_down(d1, off);
        d2 += __shfl_down(d2, off);
    }
    if (lane == 0) {
        float inv = 1.f / fmaxf(sqrtf(sq), 1e-12f);
        out[node * 3 + 0] = d0 * inv + bm[0];
        out[node * 3 + 1] = d1 * inv + bm[1];
        out[node * 3 + 2] = d2 * inv + bm[2];
    }
}

// ---------------- host ----------------

extern "C" void kernel_launch(void* const* d_in, const int* in_sizes, int n_in,
                              void* d_out, int out_size, void* d_ws, size_t ws_size,
                              hipStream_t stream) {
    const float* x  = (const float*)d_in[0];
    const int*   ei = (const int*)d_in[1];
    const float* W1 = (const float*)d_in[2];
    const float* b1 = (const float*)d_in[3];
    const float* W2 = (const float*)d_in[4];
    const float* b2 = (const float*)d_in[5];
    const float* W3 = (const float*)d_in[6];
    const float* b3 = (const float*)d_in[7];
    const float* W4 = (const float*)d_in[8];
    const float* b4 = (const float*)d_in[9];
    const float* g1 = (const float*)d_in[10];
    const float* be1 = (const float*)d_in[11];
    const float* g2 = (const float*)d_in[12];
    const float* be2 = (const float*)d_in[13];
    const float* g3 = (const float*)d_in[14];
    const float* be3 = (const float*)d_in[15];
    const float* Wm = (const float*)d_in[16];
    const float* bm = (const float*)d_in[17];
    float* out = (float*)d_out;

    const int N = in_sizes[0] / 3;
    const int E = in_sizes[1] / 2;
    const size_t NH = (size_t)N * HDIM;
    const int* src = ei;
    const int* dst = ei + E;

    // ---- workspace layout ----
    char* base = (char*)d_ws;
    int* partS  = (int*)base;            base += (size_t)NSLICE * N * 4;
    int* partD  = (int*)base;            base += (size_t)NSLICE * N * 4;
    int* degD   = (int*)base;            base += (size_t)N * 4;
    int* cursor = (int*)base;            base += (size_t)N * 4;
    int* rp     = (int*)base;            base += (size_t)(N + 2) * 4;
    int* bsum   = (int*)base;            base += (size_t)1024 * 4;
    int* perm   = (int*)base;            base += (size_t)N * 4;
    int2* ev    = (int2*)base;           base += (size_t)E * 8;
    float* dinv = (float*)base;          base += (size_t)N * 4;
    __half* Za  = (__half*)base;         base += NH * 2;
    __half* Zb  = (__half*)base;         base += NH * 2;
    __half* T1  = (__half*)base;         base += NH * 2;
    __half* T2  = (__half*)base;         base += NH * 2;
    __half* T3  = (__half*)base;         base += NH * 2;
    float* Zf   = (float*)base;          base += NH * 4;   // layer-4 out, fp32
    float* x1   = (float*)base;          base += (size_t)N * 3 * 4;
    float* x2   = (float*)base;          base += (size_t)N * 3 * 4;
    float* x3   = (float*)base;          base += (size_t)N * 3 * 4;
    float* stats = (float*)base;         base += (size_t)NSLOT * 256 * 4;
    float* bnp1  = (float*)base;         base += 256 * 4;
    float* bnp2  = (float*)base;         base += 256 * 4;
    float* bnp3  = (float*)base;         base += 256 * 4;
    _Float16* Wt = (_Float16*)base;      base += (size_t)65536 * 2;
    float* bias2 = (float*)base;         base += 128 * 4;
    int* bcnt   = (int*)base;            base += (size_t)256 * 256 * 4;
    int* boff   = (int*)base;            base += (size_t)256 * 256 * 4;

    const int EB = (E + 255) / 256;
    const int NB = (N + 255) / 256;
    const int GB = (N + 31) / 32;         // mfma gemm row tiles (32 rows)
    const int PB = (N + 3) / 4;           // pull128 blocks (4 nodes/block)
    const int NSEG = (N + SEGSZ - 1) / SEGSZ;
    const float invN = 1.f / (float)N;
    const size_t STB = (size_t)NSLOT * 256 * 4;

    // --- CSR build + edge weights + degree-ordered perm ---
    hipMemsetAsync(cursor, 0, (size_t)N * 4, stream);
    hist_kernel<<<NSEG * NSLICE, 256, 0, stream>>>(src, dst, partS, partD, NSEG, N, E);
    reduce_kernel<<<NB, 256, 0, stream>>>(partS, partD, dinv, degD, N);
    scanp1_kernel<<<NB, 256, 0, stream>>>(degD, bsum, N);
    scanp2_kernel<<<1, 1024, 0, stream>>>(bsum, NB);
    scanp3_kernel<<<NB, 256, 0, stream>>>(degD, bsum, rp, N, E);
    scatter_kernel<<<EB, 256, 0, stream>>>(src, dst, dinv, rp, cursor, ev, E);
    bcnt_kernel<<<NB, 256, 0, stream>>>(degD, bcnt, N);
    bscan_kernel<<<1, 256, 0, stream>>>(bcnt, boff, NB);
    bscat_kernel<<<NB, 256, 0, stream>>>(degD, boff, perm, N);

    // --- layer 1 (dim 3) -> Za (fp16), bnp1 ---
    pull3<<<NB, 256, 0, stream>>>(x,  nullptr, rp, ev, x1, 1.f, N);
    pull3<<<NB, 256, 0, stream>>>(x1, x,       rp, ev, x2, 2.f, N);
    pull3<<<NB, 256, 0, stream>>>(x2, x1,      rp, ev, x3, 2.f, N);
    hipMemsetAsync(stats, 0, STB, stream);
    gemm1_kernel<<<512, 256, 0, stream>>>(x, x1, x2, x3, W1, b1, Za, stats, N);
    bnfin_kernel<<<1, 128, 0, stream>>>(stats, g1, be1, bnp1, invN);

    // --- layer 2 (leaky + BN): U-chain from BN(Za,bnp1) -> Zb, bnp2 ---
    wprep_kernel<<<256, 256, 0, stream>>>(W2, bnp1, Wt);
    bias2_kernel<<<1, 128, 0, stream>>>(W2, bnp1, b2, bias2);
    pull128<1><<<PB, 256, 0, stream>>>(Za, rp, ev, perm, bnp1, T1, N);
    pull128<0><<<PB, 256, 0, stream>>>(T1, rp, ev, perm, nullptr, T2, N);
    pull128<0><<<PB, 256, 0, stream>>>(T2, rp, ev, perm, nullptr, T3, N);
    gemm_mfma<1, 1><<<GB, 256, 0, stream>>>(Za, T1, T2, T3, Wt, bias2, Zb, nullptr, N);
    hipMemsetAsync(stats, 0, STB, stream);
    bnstats_kernel<<<512, 256, 0, stream>>>(Zb, stats, N);
    bnfin_kernel<<<1, 128, 0, stream>>>(stats, g2, be2, bnp2, invN);

    // --- layer 3 (relu + BN): U-chain from BN(Zb,bnp2) -> Za, bnp3 ---
    wprep_kernel<<<256, 256, 0, stream>>>(W3, bnp2, Wt);
    bias2_kernel<<<1, 128, 0, stream>>>(W3, bnp2, b3, bias2);
    pull128<1><<<PB, 256, 0, stream>>>(Zb, rp, ev, perm, bnp2, T1, N);
    pull128<0><<<PB, 256, 0, stream>>>(T1, rp, ev, perm, nullptr, T2, N);
    pull128<0><<<PB, 256, 0, stream>>>(T2, rp, ev, perm, nullptr, T3, N);
    gemm_mfma<2, 1><<<GB, 256, 0, stream>>>(Zb, T1, T2, T3, Wt, bias2, Za, nullptr, N);
    hipMemsetAsync(stats, 0, STB, stream);
    bnstats_kernel<<<512, 256, 0, stream>>>(Za, stats, N);
    bnfin_kernel<<<1, 128, 0, stream>>>(stats, g3, be3, bnp3, invN);

    // --- layer 4 (no act/BN): U-chain from BN(Za,bnp3) -> Zf (fp32) ---
    wprep_kernel<<<256, 256, 0, stream>>>(W4, bnp3, Wt);
    bias2_kernel<<<1, 128, 0, stream>>>(W4, bnp3, b4, bias2);
    pull128<1><<<PB, 256, 0, stream>>>(Za, rp, ev, perm, bnp3, T1, N);
    pull128<0><<<PB, 256, 0, stream>>>(T1, rp, ev, perm, nullptr, T2, N);
    pull128<0><<<PB, 256, 0, stream>>>(T2, rp, ev, perm, nullptr, T3, N);
    gemm_mfma<0, 0><<<GB, 256, 0, stream>>>(Za, T1, T2, T3, Wt, bias2, nullptr, Zf, N);

    // --- normalize + project ---
    final_kernel<<<(N * 64 + 255) / 256, 256, 0, stream>>>(Zf, Wm, bm, out, N);
}

// Round 18
// 731.284 us; speedup vs baseline: 1.1410x; 1.1410x over previous
//
#include <hip/hip_runtime.h>
#include <hip/hip_fp16.h>
#include <math.h>

#define HDIM 128
#define NSLOT 32    // stats copies to spread atomic contention
#define SEGSZ 6272  // histogram segment size (LDS ints)
#define NSLICE 64   // edge slices for histogram

typedef _Float16 f16x8 __attribute__((ext_vector_type(8)));
typedef float f32x4 __attribute__((ext_vector_type(4)));

// ---------------- degree histograms via LDS segments (no global atomics) ----
__global__ __launch_bounds__(256)
void hist_kernel(const int* __restrict__ src, const int* __restrict__ dst,
                 int* __restrict__ partS, int* __restrict__ partD,
                 int nseg, int N, int E) {
    __shared__ int hS[SEGSZ];
    __shared__ int hD[SEGSZ];
    int tid = threadIdx.x;
    int seg = blockIdx.x % nseg;
    int slice = blockIdx.x / nseg;
    int seg0 = seg * SEGSZ;
    for (int i = tid; i < SEGSZ; i += 256) { hS[i] = 0; hD[i] = 0; }
    __syncthreads();
    int chunk = (E + NSLICE - 1) / NSLICE;
    int e0 = slice * chunk;
    int e1 = min(E, e0 + chunk);
    for (int e = e0 + tid; e < e1; e += 256) {
        int s = src[e] - seg0;
        int d = dst[e] - seg0;
        if ((unsigned)s < SEGSZ) atomicAdd(&hS[s], 1);
        if ((unsigned)d < SEGSZ) atomicAdd(&hD[d], 1);
    }
    __syncthreads();
    for (int i = tid; i < SEGSZ; i += 256) {
        int node = seg0 + i;
        if (node < N) {
            partS[(size_t)slice * N + node] = hS[i];
            partD[(size_t)slice * N + node] = hD[i];
        }
    }
}

// reduce partials -> dinv (fused rsqrt) and degD
__global__ void reduce_kernel(const int* __restrict__ partS, const int* __restrict__ partD,
                              float* __restrict__ dinv, int* __restrict__ degD, int N) {
    int i = blockIdx.x * blockDim.x + threadIdx.x;
    if (i >= N) return;
    int sS = 0, sD = 0;
#pragma unroll 8
    for (int k = 0; k < NSLICE; ++k) {
        sS += partS[(size_t)k * N + i];
        sD += partD[(size_t)k * N + i];
    }
    dinv[i] = sS > 0 ? rsqrtf((float)sS) : 0.f;
    degD[i] = sD;
}

// ---- 3-phase multi-block exclusive scan of degD -> rp[0..N] ----
__global__ void scanp1_kernel(const int* __restrict__ deg, int* __restrict__ bsum, int N) {
    __shared__ int sdata[256];
    int i = blockIdx.x * 256 + threadIdx.x;
    sdata[threadIdx.x] = i < N ? deg[i] : 0;
    __syncthreads();
    for (int off = 128; off > 0; off >>= 1) {
        if (threadIdx.x < off) sdata[threadIdx.x] += sdata[threadIdx.x + off];
        __syncthreads();
    }
    if (threadIdx.x == 0) bsum[blockIdx.x] = sdata[0];
}

__global__ __launch_bounds__(1024)
void scanp2_kernel(int* __restrict__ bsum, int nb) {
    __shared__ int part[1024];
    int tid = threadIdx.x;
    int v = tid < nb ? bsum[tid] : 0;
    part[tid] = v;
    __syncthreads();
    for (int off = 1; off < 1024; off <<= 1) {
        int t = tid >= off ? part[tid - off] : 0;
        __syncthreads();
        part[tid] += t;
        __syncthreads();
    }
    if (tid < nb) bsum[tid] = part[tid] - v;   // exclusive
}

__global__ void scanp3_kernel(const int* __restrict__ deg, const int* __restrict__ bsum,
                              int* __restrict__ rp, int N, int E) {
    __shared__ int part[256];
    int tid = threadIdx.x;
    int i = blockIdx.x * 256 + tid;
    int v = i < N ? deg[i] : 0;
    part[tid] = v;
    __syncthreads();
    for (int off = 1; off < 256; off <<= 1) {
        int t = tid >= off ? part[tid - off] : 0;
        __syncthreads();
        part[tid] += t;
        __syncthreads();
    }
    if (i < N) rp[i] = bsum[blockIdx.x] + part[tid] - v;
    if (i == 0) rp[N] = E;
}

__global__ void scatter_kernel(const int* __restrict__ src, const int* __restrict__ dst,
                               const float* __restrict__ dinv, const int* __restrict__ rp,
                               int* __restrict__ cursor, int2* __restrict__ ev, int E) {
    int e = blockIdx.x * blockDim.x + threadIdx.x;
    if (e >= E) return;
    int s = src[e], d = dst[e];
    float w = -dinv[s] * dinv[d];
    int pos = atomicAdd(&cursor[d], 1);
    ev[rp[d] + pos] = make_int2(s, __float_as_int(w));
}

// ---------------- pure pull: out = L * g(t) ---------------------------------
template <int GBN>
__global__ __launch_bounds__(256)
void pull128(const __half* __restrict__ t, const int* __restrict__ rp,
             const int2* __restrict__ ev, const float* __restrict__ bnp,
             __half* __restrict__ outp, int N) {
    int node = blockIdx.x * 4 + (threadIdx.x >> 6);
    if (node >= N) return;
    int lane = threadIdx.x & 63;
    int c8 = (lane & 15) * 8;     // 8-channel group
    int slot = lane >> 4;         // edge slot 0..3
    const _Float16* tp = (const _Float16*)t;

    float scv[8], shv[8];
    if (GBN) {
#pragma unroll
        for (int i = 0; i < 8; ++i) { scv[i] = bnp[c8 + i]; shv[i] = bnp[128 + c8 + i]; }
    }

    int b = rp[node], e = rp[node + 1];
    float acc0[8] = {}, acc1[8] = {};
    int j = b;
    for (; j + 8 <= e; j += 8) {
        int2 s0 = ev[j + slot];
        int2 s1 = ev[j + 4 + slot];
        f16x8 r0 = *(const f16x8*)(tp + (size_t)s0.x * HDIM + c8);
        f16x8 r1 = *(const f16x8*)(tp + (size_t)s1.x * HDIM + c8);
        float w0 = __int_as_float(s0.y), w1 = __int_as_float(s1.y);
#pragma unroll
        for (int i = 0; i < 8; ++i) {
            float v0 = (float)r0[i], v1 = (float)r1[i];
            if (GBN) { v0 = v0 * scv[i] + shv[i]; v1 = v1 * scv[i] + shv[i]; }
            acc0[i] += w0 * v0; acc1[i] += w1 * v1;
        }
    }
    for (; j < e; j += 4) {
        int idx = j + slot;
        if (idx < e) {
            int2 s0 = ev[idx];
            f16x8 r0 = *(const f16x8*)(tp + (size_t)s0.x * HDIM + c8);
            float w0 = __int_as_float(s0.y);
#pragma unroll
            for (int i = 0; i < 8; ++i) {
                float v0 = (float)r0[i];
                if (GBN) v0 = v0 * scv[i] + shv[i];
                acc0[i] += w0 * v0;
            }
        }
    }
    float s[8];
#pragma unroll
    for (int i = 0; i < 8; ++i) {
        s[i] = acc0[i] + acc1[i];
        s[i] += __shfl_xor(s[i], 16);
        s[i] += __shfl_xor(s[i], 32);
    }
    if (lane < 16) {
        size_t o = (size_t)node * HDIM + c8;
        f16x8 h;
#pragma unroll
        for (int i = 0; i < 8; ++i) h[i] = (_Float16)s[i];
        *(f16x8*)((_Float16*)outp + o) = h;
    }
}

__global__ void pull3(const float* __restrict__ t, const float* __restrict__ prev,
                      const int* __restrict__ rp, const int2* __restrict__ ev,
                      float* __restrict__ outp, float alpha, int N) {
    int node = blockIdx.x * blockDim.x + threadIdx.x;
    if (node >= N) return;
    int b = rp[node], e = rp[node + 1];
    float a0 = 0.f, a1 = 0.f, a2 = 0.f;
    for (int j = b; j < e; ++j) {
        int2 sw = ev[j];
        float w = __int_as_float(sw.y);
        const float* r = t + (size_t)sw.x * 3;
        a0 += w * r[0]; a1 += w * r[1]; a2 += w * r[2];
    }
    float r0 = alpha * a0, r1 = alpha * a1, r2 = alpha * a2;
    if (prev) {
        r0 -= prev[node * 3 + 0];
        r1 -= prev[node * 3 + 1];
        r2 -= prev[node * 3 + 2];
    }
    outp[node * 3 + 0] = r0;
    outp[node * 3 + 1] = r1;
    outp[node * 3 + 2] = r2;
}

// ---------------- weight prep: Chebyshev-fold + BN-fold, k-chunk-major fp16 -
__global__ void wprep_kernel(const float* __restrict__ W, const float* __restrict__ bnp,
                             _Float16* __restrict__ Wt) {
    int idx = blockIdx.x * 256 + threadIdx.x;   // 65536 = n(128) x k(512)
    int n = idx >> 9, k = idx & 511;
    int sel = k >> 7, kk = k & 127;
    int o = kk * 128 + n;
    float v;
    if (sel == 0)      v = (W[o] - W[2 * 16384 + o]) * bnp[kk];
    else if (sel == 1) v = W[16384 + o] - 3.f * W[3 * 16384 + o];
    else if (sel == 2) v = 2.f * W[2 * 16384 + o];
    else               v = 4.f * W[3 * 16384 + o];
    Wt[(size_t)((k >> 3) * 128 + n) * 8 + (k & 7)] = (_Float16)v;
}

// bias2[n] = b[n] + sum_k bnp_shift[k] * (W0[k][n] - W2[k][n])
__global__ void bias2_kernel(const float* __restrict__ W, const float* __restrict__ bnp,
                             const float* __restrict__ b, float* __restrict__ bias2) {
    int n = threadIdx.x;
    float s = b[n];
    for (int k = 0; k < 128; ++k)
        s += bnp[128 + k] * (W[k * 128 + n] - W[2 * 16384 + k * 128 + n]);
    bias2[n] = s;
}

// ---------------- MFMA Cheb GEMM with LDS-staged A (no stats) ---------------
template <int ACT, int OUTH>
__global__ __launch_bounds__(256)
void gemm_mfma(const __half* __restrict__ T0, const __half* __restrict__ T1,
               const __half* __restrict__ T2, const __half* __restrict__ T3,
               const _Float16* __restrict__ Wt, const float* __restrict__ bias2,
               __half* __restrict__ outh, float* __restrict__ outf, int N) {
    __shared__ __align__(16) _Float16 As[4][32][136];
    int tid = threadIdx.x;
    int wave = tid >> 6, lane = tid & 63;
    int row0 = blockIdx.x * 32;

    // ---- stage A: wave w loads table w (32 rows x 128 ch fp16 = 8 KB) ----
    {
        const __half* Ts[4] = {T0, T1, T2, T3};
        const _Float16* Tp = (const _Float16*)Ts[wave];
        int lr = lane >> 4;           // row-sub 0..3
        int ko = (lane & 15) * 8;     // k offset (halves)
        f16x8 v[8];
#pragma unroll
        for (int t = 0; t < 8; ++t) {
            int gr = min(row0 + t * 4 + lr, N - 1);
            v[t] = *(const f16x8*)(Tp + (size_t)gr * HDIM + ko);
        }
#pragma unroll
        for (int t = 0; t < 8; ++t)
            *(f16x8*)&As[wave][t * 4 + lr][ko] = v[t];
    }
    __syncthreads();

    int wr = wave >> 1, wc = wave & 1;
    int m = lane & 15, quad = lane >> 4;
    int nbase = wc * 64 + m;

    f32x4 acc[4];
#pragma unroll
    for (int ct = 0; ct < 4; ++ct) acc[ct] = (f32x4){0.f, 0.f, 0.f, 0.f};

#pragma unroll
    for (int kt = 0; kt < 4; ++kt) {
#pragma unroll
        for (int sel = 0; sel < 4; ++sel) {
            f16x8 a = *(const f16x8*)&As[sel][wr * 16 + m][kt * 32 + quad * 8];
            int c0 = sel * 16 + kt * 4 + quad;        // k-chunk index
#pragma unroll
            for (int ct = 0; ct < 4; ++ct) {
                f16x8 b0 = *(const f16x8*)(Wt + ((size_t)c0 * 128 + nbase + ct * 16) * 8);
                acc[ct] = __builtin_amdgcn_mfma_f32_16x16x32_f16(a, b0, acc[ct], 0, 0, 0);
            }
        }
    }

    // epilogue
#pragma unroll
    for (int ct = 0; ct < 4; ++ct) {
        int col = wc * 64 + ct * 16 + m;
        float bv = bias2[col];
#pragma unroll
        for (int r = 0; r < 4; ++r) {
            int drow = row0 + wr * 16 + quad * 4 + r;
            if (drow < N) {
                float v = acc[ct][r] + bv;
                if (ACT == 1) v = v >= 0.f ? v : 0.01f * v;
                else if (ACT == 2) v = fmaxf(v, 0.f);
                if (OUTH) outh[(size_t)drow * HDIM + col] = __float2half(v);
                else      outf[(size_t)drow * HDIM + col] = v;
            }
        }
    }
}

// ---------------- BN stats over fp16 Z (grid-stride streaming) --------------
__global__ __launch_bounds__(256)
void bnstats_kernel(const __half* __restrict__ Z, float* __restrict__ stats, int N) {
    __shared__ float s_sum[128];
    __shared__ float s_sq[128];
    int tid = threadIdx.x;
    int c = tid & 127;
    if (tid < 128) { s_sum[tid] = 0.f; s_sq[tid] = 0.f; }
    __syncthreads();
    float ls = 0.f, lq = 0.f;
    for (int row = blockIdx.x * 2 + (tid >> 7); row < N; row += gridDim.x * 2) {
        float v = __half2float(Z[(size_t)row * HDIM + c]);
        ls += v; lq += v * v;
    }
    atomicAdd(&s_sum[c], ls);
    atomicAdd(&s_sq[c], lq);
    __syncthreads();
    if (tid < 128) {
        float* sp = stats + (size_t)(blockIdx.x & (NSLOT - 1)) * 256;
        atomicAdd(&sp[tid], s_sum[tid]);
        atomicAdd(&sp[128 + tid], s_sq[tid]);
    }
}

// ---------------- layer-1 (input dim 3) fused GEMM, grid-stride ------------
__global__ __launch_bounds__(256)
void gemm1_kernel(const float* __restrict__ x, const float* __restrict__ t1,
                  const float* __restrict__ t2, const float* __restrict__ t3,
                  const float* __restrict__ W1, const float* __restrict__ b1,
                  __half* __restrict__ out, float* __restrict__ stats, int N) {
    __shared__ float s_sum[128];
    __shared__ float s_sq[128];
    int tid = threadIdx.x;
    int c = tid & 127;
    if (tid < 128) { s_sum[tid] = 0.f; s_sq[tid] = 0.f; }
    __syncthreads();
    float wreg[12];
#pragma unroll
    for (int i = 0; i < 12; ++i) wreg[i] = W1[i * 128 + c];
    float bias = b1[c];
    const float* Ts[4] = {x, t1, t2, t3};
    float lsum = 0.f, lsq = 0.f;
    for (int row = blockIdx.x * 2 + (tid >> 7); row < N; row += gridDim.x * 2) {
        float v = bias;
#pragma unroll
        for (int k = 0; k < 4; ++k) {
            const float* t = Ts[k];
#pragma unroll
            for (int d = 0; d < 3; ++d)
                v += t[row * 3 + d] * wreg[k * 3 + d];
        }
        v = v >= 0.f ? v : 0.01f * v;   // leaky_relu
        out[(size_t)row * HDIM + c] = __float2half(v);
        lsum += v; lsq += v * v;
    }
    atomicAdd(&s_sum[c], lsum);
    atomicAdd(&s_sq[c], lsq);
    __syncthreads();
    if (tid < 128) {
        float* sp = stats + (size_t)(blockIdx.x & (NSLOT - 1)) * 256;
        atomicAdd(&sp[tid], s_sum[tid]);
        atomicAdd(&sp[128 + tid], s_sq[tid]);
    }
}

// ---------------- BN finalize: reduce NSLOT stats copies -> (scale, shift) --
__global__ void bnfin_kernel(const float* __restrict__ stats, const float* __restrict__ g,
                             const float* __restrict__ be, float* __restrict__ bnp, float invN) {
    int c = threadIdx.x;  // 128 threads
    float s0 = 0.f, s1 = 0.f;
#pragma unroll 4
    for (int k = 0; k < NSLOT; ++k) {
        s0 += stats[k * 256 + c];
        s1 += stats[k * 256 + 128 + c];
    }
    float m = s0 * invN;
    float v = s1 * invN - m * m;
    float sc = g[c] * rsqrtf(v + 1e-5f);
    bnp[c] = sc;
    bnp[128 + c] = be[c] - m * sc;
}

// ---------------- final: L2-normalize row + project to 3 ----------------
__global__ void final_kernel(const float* __restrict__ Z, const float* __restrict__ Wm,
                             const float* __restrict__ bm, float* __restrict__ out, int N) {
    int gid = blockIdx.x * blockDim.x + threadIdx.x;
    int node = gid >> 6;
    int lane = threadIdx.x & 63;
    if (node >= N) return;
    const float* z = Z + (size_t)node * HDIM;
    float z0 = z[lane], z1 = z[lane + 64];
    float sq = z0 * z0 + z1 * z1;
    float d0 = z0 * Wm[lane * 3 + 0] + z1 * Wm[(lane + 64) * 3 + 0];
    float d1 = z0 * Wm[lane * 3 + 1] + z1 * Wm[(lane + 64) * 3 + 1];
    float d2 = z0 * Wm[lane * 3 + 2] + z1 * Wm[(lane + 64) * 3 + 2];
#pragma unroll
    for (int off = 32; off > 0; off >>= 1) {
        sq += __shfl_down(sq, off);
        d0 += __shfl_down(d0, off);
        d1 += __shfl_down(d1, off);
        d2 += __shfl_down(d2, off);
    }
    if (lane == 0) {
        float inv = 1.f / fmaxf(sqrtf(sq), 1e-12f);
        out[node * 3 + 0] = d0 * inv + bm[0];
        out[node * 3 + 1] = d1 * inv + bm[1];
        out[node * 3 + 2] = d2 * inv + bm[2];
    }
}

// ---------------- host ----------------

extern "C" void kernel_launch(void* const* d_in, const int* in_sizes, int n_in,
                              void* d_out, int out_size, void* d_ws, size_t ws_size,
                              hipStream_t stream) {
    const float* x  = (const float*)d_in[0];
    const int*   ei = (const int*)d_in[1];
    const float* W1 = (const float*)d_in[2];
    const float* b1 = (const float*)d_in[3];
    const float* W2 = (const float*)d_in[4];
    const float* b2 = (const float*)d_in[5];
    const float* W3 = (const float*)d_in[6];
    const float* b3 = (const float*)d_in[7];
    const float* W4 = (const float*)d_in[8];
    const float* b4 = (const float*)d_in[9];
    const float* g1 = (const float*)d_in[10];
    const float* be1 = (const float*)d_in[11];
    const float* g2 = (const float*)d_in[12];
    const float* be2 = (const float*)d_in[13];
    const float* g3 = (const float*)d_in[14];
    const float* be3 = (const float*)d_in[15];
    const float* Wm = (const float*)d_in[16];
    const float* bm = (const float*)d_in[17];
    float* out = (float*)d_out;

    const int N = in_sizes[0] / 3;
    const int E = in_sizes[1] / 2;
    const size_t NH = (size_t)N * HDIM;
    const int* src = ei;
    const int* dst = ei + E;

    // ---- workspace layout ----
    char* base = (char*)d_ws;
    int* partS  = (int*)base;            base += (size_t)NSLICE * N * 4;
    int* partD  = (int*)base;            base += (size_t)NSLICE * N * 4;
    int* degD   = (int*)base;            base += (size_t)N * 4;
    int* cursor = (int*)base;            base += (size_t)N * 4;
    int* rp     = (int*)base;            base += (size_t)(N + 2) * 4;
    int* bsum   = (int*)base;            base += (size_t)1024 * 4;
    int2* ev    = (int2*)base;           base += (size_t)E * 8;
    float* dinv = (float*)base;          base += (size_t)N * 4;
    __half* Za  = (__half*)base;         base += NH * 2;
    __half* Zb  = (__half*)base;         base += NH * 2;
    __half* T1  = (__half*)base;         base += NH * 2;
    __half* T2  = (__half*)base;         base += NH * 2;
    __half* T3  = (__half*)base;         base += NH * 2;
    float* Zf   = (float*)base;          base += NH * 4;   // layer-4 out, fp32
    float* x1   = (float*)base;          base += (size_t)N * 3 * 4;
    float* x2   = (float*)base;          base += (size_t)N * 3 * 4;
    float* x3   = (float*)base;          base += (size_t)N * 3 * 4;
    float* stats = (float*)base;         base += (size_t)NSLOT * 256 * 4;
    float* bnp1  = (float*)base;         base += 256 * 4;
    float* bnp2  = (float*)base;         base += 256 * 4;
    float* bnp3  = (float*)base;         base += 256 * 4;
    _Float16* Wt = (_Float16*)base;      base += (size_t)65536 * 2;
    float* bias2 = (float*)base;         base += 128 * 4;

    const int EB = (E + 255) / 256;
    const int NB = (N + 255) / 256;
    const int GB = (N + 31) / 32;         // mfma gemm row tiles (32 rows)
    const int PB = (N + 3) / 4;           // pull128 blocks (4 nodes/block)
    const int NSEG = (N + SEGSZ - 1) / SEGSZ;
    const float invN = 1.f / (float)N;
    const size_t STB = (size_t)NSLOT * 256 * 4;

    // --- CSR build + edge weights ---
    hipMemsetAsync(cursor, 0, (size_t)N * 4, stream);
    hist_kernel<<<NSEG * NSLICE, 256, 0, stream>>>(src, dst, partS, partD, NSEG, N, E);
    reduce_kernel<<<NB, 256, 0, stream>>>(partS, partD, dinv, degD, N);
    scanp1_kernel<<<NB, 256, 0, stream>>>(degD, bsum, N);
    scanp2_kernel<<<1, 1024, 0, stream>>>(bsum, NB);
    scanp3_kernel<<<NB, 256, 0, stream>>>(degD, bsum, rp, N, E);
    scatter_kernel<<<EB, 256, 0, stream>>>(src, dst, dinv, rp, cursor, ev, E);

    // --- layer 1 (dim 3) -> Za (fp16), bnp1 ---
    pull3<<<NB, 256, 0, stream>>>(x,  nullptr, rp, ev, x1, 1.f, N);
    pull3<<<NB, 256, 0, stream>>>(x1, x,       rp, ev, x2, 2.f, N);
    pull3<<<NB, 256, 0, stream>>>(x2, x1,      rp, ev, x3, 2.f, N);
    hipMemsetAsync(stats, 0, STB, stream);
    gemm1_kernel<<<512, 256, 0, stream>>>(x, x1, x2, x3, W1, b1, Za, stats, N);
    bnfin_kernel<<<1, 128, 0, stream>>>(stats, g1, be1, bnp1, invN);

    // --- layer 2 (leaky + BN): U-chain from BN(Za,bnp1) -> Zb, bnp2 ---
    wprep_kernel<<<256, 256, 0, stream>>>(W2, bnp1, Wt);
    bias2_kernel<<<1, 128, 0, stream>>>(W2, bnp1, b2, bias2);
    pull128<1><<<PB, 256, 0, stream>>>(Za, rp, ev, bnp1, T1, N);
    pull128<0><<<PB, 256, 0, stream>>>(T1, rp, ev, nullptr, T2, N);
    pull128<0><<<PB, 256, 0, stream>>>(T2, rp, ev, nullptr, T3, N);
    gemm_mfma<1, 1><<<GB, 256, 0, stream>>>(Za, T1, T2, T3, Wt, bias2, Zb, nullptr, N);
    hipMemsetAsync(stats, 0, STB, stream);
    bnstats_kernel<<<512, 256, 0, stream>>>(Zb, stats, N);
    bnfin_kernel<<<1, 128, 0, stream>>>(stats, g2, be2, bnp2, invN);

    // --- layer 3 (relu + BN): U-chain from BN(Zb,bnp2) -> Za, bnp3 ---
    wprep_kernel<<<256, 256, 0, stream>>>(W3, bnp2, Wt);
    bias2_kernel<<<1, 128, 0, stream>>>(W3, bnp2, b3, bias2);
    pull128<1><<<PB, 256, 0, stream>>>(Zb, rp, ev, bnp2, T1, N);
    pull128<0><<<PB, 256, 0, stream>>>(T1, rp, ev, nullptr, T2, N);
    pull128<0><<<PB, 256, 0, stream>>>(T2, rp, ev, nullptr, T3, N);
    gemm_mfma<2, 1><<<GB, 256, 0, stream>>>(Zb, T1, T2, T3, Wt, bias2, Za, nullptr, N);
    hipMemsetAsync(stats, 0, STB, stream);
    bnstats_kernel<<<512, 256, 0, stream>>>(Za, stats, N);
    bnfin_kernel<<<1, 128, 0, stream>>>(stats, g3, be3, bnp3, invN);

    // --- layer 4 (no act/BN): U-chain from BN(Za,bnp3) -> Zf (fp32) ---
    wprep_kernel<<<256, 256, 0, stream>>>(W4, bnp3, Wt);
    bias2_kernel<<<1, 128, 0, stream>>>(W4, bnp3, b4, bias2);
    pull128<1><<<PB, 256, 0, stream>>>(Za, rp, ev, bnp3, T1, N);
    pull128<0><<<PB, 256, 0, stream>>>(T1, rp, ev, nullptr, T2, N);
    pull128<0><<<PB, 256, 0, stream>>>(T2, rp, ev, nullptr, T3, N);
    gemm_mfma<0, 0><<<GB, 256, 0, stream>>>(Za, T1, T2, T3, Wt, bias2, nullptr, Zf, N);

    // --- normalize + project ---
    final_kernel<<<(N * 64 + 255) / 256, 256, 0, stream>>>(Zf, Wm, bm, out, N);
}

// Round 19
// 718.567 us; speedup vs baseline: 1.1612x; 1.0177x over previous
//
#include <hip/hip_runtime.h>
#include <hip/hip_fp16.h>
#include <math.h>

#define HDIM 128
#define NSLOT 32    // stats copies to spread atomic contention
#define SEGSZ 6272  // histogram segment size (LDS ints)
#define NSLICE 64   // edge slices for histogram

typedef _Float16 f16x8 __attribute__((ext_vector_type(8)));
typedef float f32x4 __attribute__((ext_vector_type(4)));

// ---------------- degree histograms via LDS segments (no global atomics) ----
__global__ __launch_bounds__(256)
void hist_kernel(const int* __restrict__ src, const int* __restrict__ dst,
                 int* __restrict__ partS, int* __restrict__ partD,
                 int nseg, int N, int E) {
    __shared__ int hS[SEGSZ];
    __shared__ int hD[SEGSZ];
    int tid = threadIdx.x;
    int seg = blockIdx.x % nseg;
    int slice = blockIdx.x / nseg;
    int seg0 = seg * SEGSZ;
    for (int i = tid; i < SEGSZ; i += 256) { hS[i] = 0; hD[i] = 0; }
    __syncthreads();
    int chunk = (E + NSLICE - 1) / NSLICE;
    int e0 = slice * chunk;
    int e1 = min(E, e0 + chunk);
    for (int e = e0 + tid; e < e1; e += 256) {
        int s = src[e] - seg0;
        int d = dst[e] - seg0;
        if ((unsigned)s < SEGSZ) atomicAdd(&hS[s], 1);
        if ((unsigned)d < SEGSZ) atomicAdd(&hD[d], 1);
    }
    __syncthreads();
    for (int i = tid; i < SEGSZ; i += 256) {
        int node = seg0 + i;
        if (node < N) {
            partS[(size_t)slice * N + node] = hS[i];
            partD[(size_t)slice * N + node] = hD[i];
        }
    }
}

// reduce partials -> dinv (fused rsqrt) and degD
__global__ void reduce_kernel(const int* __restrict__ partS, const int* __restrict__ partD,
                              float* __restrict__ dinv, int* __restrict__ degD, int N) {
    int i = blockIdx.x * blockDim.x + threadIdx.x;
    if (i >= N) return;
    int sS = 0, sD = 0;
#pragma unroll 8
    for (int k = 0; k < NSLICE; ++k) {
        sS += partS[(size_t)k * N + i];
        sD += partD[(size_t)k * N + i];
    }
    dinv[i] = sS > 0 ? rsqrtf((float)sS) : 0.f;
    degD[i] = sD;
}

// ---- 3-phase multi-block exclusive scan of degD -> rp[0..N] ----
__global__ void scanp1_kernel(const int* __restrict__ deg, int* __restrict__ bsum, int N) {
    __shared__ int sdata[256];
    int i = blockIdx.x * 256 + threadIdx.x;
    sdata[threadIdx.x] = i < N ? deg[i] : 0;
    __syncthreads();
    for (int off = 128; off > 0; off >>= 1) {
        if (threadIdx.x < off) sdata[threadIdx.x] += sdata[threadIdx.x + off];
        __syncthreads();
    }
    if (threadIdx.x == 0) bsum[blockIdx.x] = sdata[0];
}

__global__ __launch_bounds__(1024)
void scanp2_kernel(int* __restrict__ bsum, int nb) {
    __shared__ int part[1024];
    int tid = threadIdx.x;
    int v = tid < nb ? bsum[tid] : 0;
    part[tid] = v;
    __syncthreads();
    for (int off = 1; off < 1024; off <<= 1) {
        int t = tid >= off ? part[tid - off] : 0;
        __syncthreads();
        part[tid] += t;
        __syncthreads();
    }
    if (tid < nb) bsum[tid] = part[tid] - v;   // exclusive
}

__global__ void scanp3_kernel(const int* __restrict__ deg, const int* __restrict__ bsum,
                              int* __restrict__ rp, int N, int E) {
    __shared__ int part[256];
    int tid = threadIdx.x;
    int i = blockIdx.x * 256 + tid;
    int v = i < N ? deg[i] : 0;
    part[tid] = v;
    __syncthreads();
    for (int off = 1; off < 256; off <<= 1) {
        int t = tid >= off ? part[tid - off] : 0;
        __syncthreads();
        part[tid] += t;
        __syncthreads();
    }
    if (i < N) rp[i] = bsum[blockIdx.x] + part[tid] - v;
    if (i == 0) rp[N] = E;
}

__global__ void scatter_kernel(const int* __restrict__ src, const int* __restrict__ dst,
                               const float* __restrict__ dinv, const int* __restrict__ rp,
                               int* __restrict__ cursor, int2* __restrict__ ev, int E) {
    int e = blockIdx.x * blockDim.x + threadIdx.x;
    if (e >= E) return;
    int s = src[e], d = dst[e];
    float w = -dinv[s] * dinv[d];
    int pos = atomicAdd(&cursor[d], 1);
    ev[rp[d] + pos] = make_int2(s, __float_as_int(w));
}

// ---------------- pure pull: out = L * g(t) ---------------------------------
template <int GBN>
__global__ __launch_bounds__(256)
void pull128(const __half* __restrict__ t, const int* __restrict__ rp,
             const int2* __restrict__ ev, const float* __restrict__ bnp,
             __half* __restrict__ outp, int N) {
    int node = blockIdx.x * 4 + (threadIdx.x >> 6);
    if (node >= N) return;
    int lane = threadIdx.x & 63;
    int c8 = (lane & 15) * 8;     // 8-channel group
    int slot = lane >> 4;         // edge slot 0..3
    const _Float16* tp = (const _Float16*)t;

    float scv[8], shv[8];
    if (GBN) {
#pragma unroll
        for (int i = 0; i < 8; ++i) { scv[i] = bnp[c8 + i]; shv[i] = bnp[128 + c8 + i]; }
    }

    int b = rp[node], e = rp[node + 1];
    float acc0[8] = {}, acc1[8] = {};
    int j = b;
    for (; j + 8 <= e; j += 8) {
        int2 s0 = ev[j + slot];
        int2 s1 = ev[j + 4 + slot];
        f16x8 r0 = *(const f16x8*)(tp + (size_t)s0.x * HDIM + c8);
        f16x8 r1 = *(const f16x8*)(tp + (size_t)s1.x * HDIM + c8);
        float w0 = __int_as_float(s0.y), w1 = __int_as_float(s1.y);
#pragma unroll
        for (int i = 0; i < 8; ++i) {
            float v0 = (float)r0[i], v1 = (float)r1[i];
            if (GBN) { v0 = v0 * scv[i] + shv[i]; v1 = v1 * scv[i] + shv[i]; }
            acc0[i] += w0 * v0; acc1[i] += w1 * v1;
        }
    }
    for (; j < e; j += 4) {
        int idx = j + slot;
        if (idx < e) {
            int2 s0 = ev[idx];
            f16x8 r0 = *(const f16x8*)(tp + (size_t)s0.x * HDIM + c8);
            float w0 = __int_as_float(s0.y);
#pragma unroll
            for (int i = 0; i < 8; ++i) {
                float v0 = (float)r0[i];
                if (GBN) v0 = v0 * scv[i] + shv[i];
                acc0[i] += w0 * v0;
            }
        }
    }
    float s[8];
#pragma unroll
    for (int i = 0; i < 8; ++i) {
        s[i] = acc0[i] + acc1[i];
        s[i] += __shfl_xor(s[i], 16);
        s[i] += __shfl_xor(s[i], 32);
    }
    if (lane < 16) {
        size_t o = (size_t)node * HDIM + c8;
        f16x8 h;
#pragma unroll
        for (int i = 0; i < 8; ++i) h[i] = (_Float16)s[i];
        *(f16x8*)((_Float16*)outp + o) = h;
    }
}

__global__ void pull3(const float* __restrict__ t, const float* __restrict__ prev,
                      const int* __restrict__ rp, const int2* __restrict__ ev,
                      float* __restrict__ outp, float alpha, int N) {
    int node = blockIdx.x * blockDim.x + threadIdx.x;
    if (node >= N) return;
    int b = rp[node], e = rp[node + 1];
    float a0 = 0.f, a1 = 0.f, a2 = 0.f;
    for (int j = b; j < e; ++j) {
        int2 sw = ev[j];
        float w = __int_as_float(sw.y);
        const float* r = t + (size_t)sw.x * 3;
        a0 += w * r[0]; a1 += w * r[1]; a2 += w * r[2];
    }
    float r0 = alpha * a0, r1 = alpha * a1, r2 = alpha * a2;
    if (prev) {
        r0 -= prev[node * 3 + 0];
        r1 -= prev[node * 3 + 1];
        r2 -= prev[node * 3 + 2];
    }
    outp[node * 3 + 0] = r0;
    outp[node * 3 + 1] = r1;
    outp[node * 3 + 2] = r2;
}

// ---------------- fused BN-finalize + weight prep + bias --------------------
// Blocks 0..255: Wt[((k>>3)*128+n)*8+(k&7)] from Chebyshev-folded W with BN
//   scale (sel==0) computed inline from raw stats (no cross-block dependency).
// Block 256: compute full (scale,shift) -> bnp (for pulls), then bias2.
__global__ __launch_bounds__(256)
void wfuse_kernel(const float* __restrict__ stats, const float* __restrict__ g,
                  const float* __restrict__ be, const float* __restrict__ W,
                  const float* __restrict__ b, _Float16* __restrict__ Wt,
                  float* __restrict__ bias2, float* __restrict__ bnp, float invN) {
    int tid = threadIdx.x;
    if (blockIdx.x < 256) {
        int idx = blockIdx.x * 256 + tid;   // 65536 = n(128) x k(512)
        int n = idx >> 9, k = idx & 511;
        int sel = k >> 7, kk = k & 127;
        int o = kk * 128 + n;
        float v;
        if (sel == 0) {
            float s0 = 0.f, s1 = 0.f;
#pragma unroll 4
            for (int t = 0; t < NSLOT; ++t) {
                s0 += stats[t * 256 + kk];
                s1 += stats[t * 256 + 128 + kk];
            }
            float m = s0 * invN;
            float var = s1 * invN - m * m;
            float sc = g[kk] * rsqrtf(var + 1e-5f);
            v = (W[o] - W[2 * 16384 + o]) * sc;
        } else if (sel == 1) v = W[16384 + o] - 3.f * W[3 * 16384 + o];
        else if (sel == 2)   v = 2.f * W[2 * 16384 + o];
        else                 v = 4.f * W[3 * 16384 + o];
        Wt[(size_t)((k >> 3) * 128 + n) * 8 + (k & 7)] = (_Float16)v;
    } else {
        __shared__ float sh[128];
        if (tid < 128) {
            float s0 = 0.f, s1 = 0.f;
#pragma unroll 4
            for (int t = 0; t < NSLOT; ++t) {
                s0 += stats[t * 256 + tid];
                s1 += stats[t * 256 + 128 + tid];
            }
            float m = s0 * invN;
            float var = s1 * invN - m * m;
            float sc = g[tid] * rsqrtf(var + 1e-5f);
            float shf = be[tid] - m * sc;
            bnp[tid] = sc;
            bnp[128 + tid] = shf;
            sh[tid] = shf;
        }
        __syncthreads();
        if (tid < 128) {
            float s = b[tid];
            for (int k = 0; k < 128; ++k)
                s += sh[k] * (W[k * 128 + tid] - W[2 * 16384 + k * 128 + tid]);
            bias2[tid] = s;
        }
    }
}

// ---------------- MFMA Cheb GEMM with LDS-staged A (no stats) ---------------
template <int ACT, int OUTH>
__global__ __launch_bounds__(256)
void gemm_mfma(const __half* __restrict__ T0, const __half* __restrict__ T1,
               const __half* __restrict__ T2, const __half* __restrict__ T3,
               const _Float16* __restrict__ Wt, const float* __restrict__ bias2,
               __half* __restrict__ outh, float* __restrict__ outf, int N) {
    __shared__ __align__(16) _Float16 As[4][32][136];
    int tid = threadIdx.x;
    int wave = tid >> 6, lane = tid & 63;
    int row0 = blockIdx.x * 32;

    // ---- stage A: wave w loads table w (32 rows x 128 ch fp16 = 8 KB) ----
    {
        const __half* Ts[4] = {T0, T1, T2, T3};
        const _Float16* Tp = (const _Float16*)Ts[wave];
        int lr = lane >> 4;           // row-sub 0..3
        int ko = (lane & 15) * 8;     // k offset (halves)
        f16x8 v[8];
#pragma unroll
        for (int t = 0; t < 8; ++t) {
            int gr = min(row0 + t * 4 + lr, N - 1);
            v[t] = *(const f16x8*)(Tp + (size_t)gr * HDIM + ko);
        }
#pragma unroll
        for (int t = 0; t < 8; ++t)
            *(f16x8*)&As[wave][t * 4 + lr][ko] = v[t];
    }
    __syncthreads();

    int wr = wave >> 1, wc = wave & 1;
    int m = lane & 15, quad = lane >> 4;
    int nbase = wc * 64 + m;

    f32x4 acc[4];
#pragma unroll
    for (int ct = 0; ct < 4; ++ct) acc[ct] = (f32x4){0.f, 0.f, 0.f, 0.f};

#pragma unroll
    for (int kt = 0; kt < 4; ++kt) {
#pragma unroll
        for (int sel = 0; sel < 4; ++sel) {
            f16x8 a = *(const f16x8*)&As[sel][wr * 16 + m][kt * 32 + quad * 8];
            int c0 = sel * 16 + kt * 4 + quad;        // k-chunk index
#pragma unroll
            for (int ct = 0; ct < 4; ++ct) {
                f16x8 b0 = *(const f16x8*)(Wt + ((size_t)c0 * 128 + nbase + ct * 16) * 8);
                acc[ct] = __builtin_amdgcn_mfma_f32_16x16x32_f16(a, b0, acc[ct], 0, 0, 0);
            }
        }
    }

    // epilogue
#pragma unroll
    for (int ct = 0; ct < 4; ++ct) {
        int col = wc * 64 + ct * 16 + m;
        float bv = bias2[col];
#pragma unroll
        for (int r = 0; r < 4; ++r) {
            int drow = row0 + wr * 16 + quad * 4 + r;
            if (drow < N) {
                float v = acc[ct][r] + bv;
                if (ACT == 1) v = v >= 0.f ? v : 0.01f * v;
                else if (ACT == 2) v = fmaxf(v, 0.f);
                if (OUTH) outh[(size_t)drow * HDIM + col] = __float2half(v);
                else      outf[(size_t)drow * HDIM + col] = v;
            }
        }
    }
}

// ---------------- BN stats over fp16 Z (grid-stride streaming) --------------
__global__ __launch_bounds__(256)
void bnstats_kernel(const __half* __restrict__ Z, float* __restrict__ stats, int N) {
    __shared__ float s_sum[128];
    __shared__ float s_sq[128];
    int tid = threadIdx.x;
    int c = tid & 127;
    if (tid < 128) { s_sum[tid] = 0.f; s_sq[tid] = 0.f; }
    __syncthreads();
    float ls = 0.f, lq = 0.f;
    for (int row = blockIdx.x * 2 + (tid >> 7); row < N; row += gridDim.x * 2) {
        float v = __half2float(Z[(size_t)row * HDIM + c]);
        ls += v; lq += v * v;
    }
    atomicAdd(&s_sum[c], ls);
    atomicAdd(&s_sq[c], lq);
    __syncthreads();
    if (tid < 128) {
        float* sp = stats + (size_t)(blockIdx.x & (NSLOT - 1)) * 256;
        atomicAdd(&sp[tid], s_sum[tid]);
        atomicAdd(&sp[128 + tid], s_sq[tid]);
    }
}

// ---------------- layer-1 (input dim 3) fused GEMM, grid-stride ------------
__global__ __launch_bounds__(256)
void gemm1_kernel(const float* __restrict__ x, const float* __restrict__ t1,
                  const float* __restrict__ t2, const float* __restrict__ t3,
                  const float* __restrict__ W1, const float* __restrict__ b1,
                  __half* __restrict__ out, float* __restrict__ stats, int N) {
    __shared__ float s_sum[128];
    __shared__ float s_sq[128];
    int tid = threadIdx.x;
    int c = tid & 127;
    if (tid < 128) { s_sum[tid] = 0.f; s_sq[tid] = 0.f; }
    __syncthreads();
    float wreg[12];
#pragma unroll
    for (int i = 0; i < 12; ++i) wreg[i] = W1[i * 128 + c];
    float bias = b1[c];
    const float* Ts[4] = {x, t1, t2, t3};
    float lsum = 0.f, lsq = 0.f;
    for (int row = blockIdx.x * 2 + (tid >> 7); row < N; row += gridDim.x * 2) {
        float v = bias;
#pragma unroll
        for (int k = 0; k < 4; ++k) {
            const float* t = Ts[k];
#pragma unroll
            for (int d = 0; d < 3; ++d)
                v += t[row * 3 + d] * wreg[k * 3 + d];
        }
        v = v >= 0.f ? v : 0.01f * v;   // leaky_relu
        out[(size_t)row * HDIM + c] = __float2half(v);
        lsum += v; lsq += v * v;
    }
    atomicAdd(&s_sum[c], lsum);
    atomicAdd(&s_sq[c], lsq);
    __syncthreads();
    if (tid < 128) {
        float* sp = stats + (size_t)(blockIdx.x & (NSLOT - 1)) * 256;
        atomicAdd(&sp[tid], s_sum[tid]);
        atomicAdd(&sp[128 + tid], s_sq[tid]);
    }
}

// ---------------- final: L2-normalize row + project to 3 ----------------
__global__ void final_kernel(const float* __restrict__ Z, const float* __restrict__ Wm,
                             const float* __restrict__ bm, float* __restrict__ out, int N) {
    int gid = blockIdx.x * blockDim.x + threadIdx.x;
    int node = gid >> 6;
    int lane = threadIdx.x & 63;
    if (node >= N) return;
    const float* z = Z + (size_t)node * HDIM;
    float z0 = z[lane], z1 = z[lane + 64];
    float sq = z0 * z0 + z1 * z1;
    float d0 = z0 * Wm[lane * 3 + 0] + z1 * Wm[(lane + 64) * 3 + 0];
    float d1 = z0 * Wm[lane * 3 + 1] + z1 * Wm[(lane + 64) * 3 + 1];
    float d2 = z0 * Wm[lane * 3 + 2] + z1 * Wm[(lane + 64) * 3 + 2];
#pragma unroll
    for (int off = 32; off > 0; off >>= 1) {
        sq += __shfl_down(sq, off);
        d0 += __shfl_down(d0, off);
        d1 += __shfl_down(d1, off);
        d2 += __shfl_down(d2, off);
    }
    if (lane == 0) {
        float inv = 1.f / fmaxf(sqrtf(sq), 1e-12f);
        out[node * 3 + 0] = d0 * inv + bm[0];
        out[node * 3 + 1] = d1 * inv + bm[1];
        out[node * 3 + 2] = d2 * inv + bm[2];
    }
}

// ---------------- host ----------------

extern "C" void kernel_launch(void* const* d_in, const int* in_sizes, int n_in,
                              void* d_out, int out_size, void* d_ws, size_t ws_size,
                              hipStream_t stream) {
    const float* x  = (const float*)d_in[0];
    const int*   ei = (const int*)d_in[1];
    const float* W1 = (const float*)d_in[2];
    const float* b1 = (const float*)d_in[3];
    const float* W2 = (const float*)d_in[4];
    const float* b2 = (const float*)d_in[5];
    const float* W3 = (const float*)d_in[6];
    const float* b3 = (const float*)d_in[7];
    const float* W4 = (const float*)d_in[8];
    const float* b4 = (const float*)d_in[9];
    const float* g1 = (const float*)d_in[10];
    const float* be1 = (const float*)d_in[11];
    const float* g2 = (const float*)d_in[12];
    const float* be2 = (const float*)d_in[13];
    const float* g3 = (const float*)d_in[14];
    const float* be3 = (const float*)d_in[15];
    const float* Wm = (const float*)d_in[16];
    const float* bm = (const float*)d_in[17];
    float* out = (float*)d_out;

    const int N = in_sizes[0] / 3;
    const int E = in_sizes[1] / 2;
    const size_t NH = (size_t)N * HDIM;
    const int* src = ei;
    const int* dst = ei + E;

    // ---- workspace layout ----
    char* base = (char*)d_ws;
    int* partS  = (int*)base;            base += (size_t)NSLICE * N * 4;
    int* partD  = (int*)base;            base += (size_t)NSLICE * N * 4;
    int* degD   = (int*)base;            base += (size_t)N * 4;
    int* cursor = (int*)base;            base += (size_t)N * 4;
    int* rp     = (int*)base;            base += (size_t)(N + 2) * 4;
    int* bsum   = (int*)base;            base += (size_t)1024 * 4;
    int2* ev    = (int2*)base;           base += (size_t)E * 8;
    float* dinv = (float*)base;          base += (size_t)N * 4;
    __half* Za  = (__half*)base;         base += NH * 2;
    __half* Zb  = (__half*)base;         base += NH * 2;
    __half* T1  = (__half*)base;         base += NH * 2;
    __half* T2  = (__half*)base;         base += NH * 2;
    __half* T3  = (__half*)base;         base += NH * 2;
    float* Zf   = (float*)base;          base += NH * 4;   // layer-4 out, fp32
    float* x1   = (float*)base;          base += (size_t)N * 3 * 4;
    float* x2   = (float*)base;          base += (size_t)N * 3 * 4;
    float* x3   = (float*)base;          base += (size_t)N * 3 * 4;
    float* stats = (float*)base;         base += (size_t)NSLOT * 256 * 4;
    float* bnp1  = (float*)base;         base += 256 * 4;
    float* bnp2  = (float*)base;         base += 256 * 4;
    float* bnp3  = (float*)base;         base += 256 * 4;
    _Float16* Wt = (_Float16*)base;      base += (size_t)65536 * 2;
    float* bias2 = (float*)base;         base += 128 * 4;

    const int EB = (E + 255) / 256;
    const int NB = (N + 255) / 256;
    const int GB = (N + 31) / 32;         // mfma gemm row tiles (32 rows)
    const int PB = (N + 3) / 4;           // pull128 blocks (4 nodes/block)
    const int NSEG = (N + SEGSZ - 1) / SEGSZ;
    const float invN = 1.f / (float)N;
    const size_t STB = (size_t)NSLOT * 256 * 4;

    // --- CSR build + edge weights ---
    hipMemsetAsync(cursor, 0, (size_t)N * 4, stream);
    hist_kernel<<<NSEG * NSLICE, 256, 0, stream>>>(src, dst, partS, partD, NSEG, N, E);
    reduce_kernel<<<NB, 256, 0, stream>>>(partS, partD, dinv, degD, N);
    scanp1_kernel<<<NB, 256, 0, stream>>>(degD, bsum, N);
    scanp2_kernel<<<1, 1024, 0, stream>>>(bsum, NB);
    scanp3_kernel<<<NB, 256, 0, stream>>>(degD, bsum, rp, N, E);
    scatter_kernel<<<EB, 256, 0, stream>>>(src, dst, dinv, rp, cursor, ev, E);

    // --- layer 1 (dim 3) -> Za (fp16) + stats ---
    pull3<<<NB, 256, 0, stream>>>(x,  nullptr, rp, ev, x1, 1.f, N);
    pull3<<<NB, 256, 0, stream>>>(x1, x,       rp, ev, x2, 2.f, N);
    pull3<<<NB, 256, 0, stream>>>(x2, x1,      rp, ev, x3, 2.f, N);
    hipMemsetAsync(stats, 0, STB, stream);
    gemm1_kernel<<<512, 256, 0, stream>>>(x, x1, x2, x3, W1, b1, Za, stats, N);

    // --- layer 2 (leaky + BN): U-chain from BN(Za,bnp1) -> Zb ---
    wfuse_kernel<<<257, 256, 0, stream>>>(stats, g1, be1, W2, b2, Wt, bias2, bnp1, invN);
    pull128<1><<<PB, 256, 0, stream>>>(Za, rp, ev, bnp1, T1, N);
    pull128<0><<<PB, 256, 0, stream>>>(T1, rp, ev, nullptr, T2, N);
    pull128<0><<<PB, 256, 0, stream>>>(T2, rp, ev, nullptr, T3, N);
    gemm_mfma<1, 1><<<GB, 256, 0, stream>>>(Za, T1, T2, T3, Wt, bias2, Zb, nullptr, N);
    hipMemsetAsync(stats, 0, STB, stream);
    bnstats_kernel<<<512, 256, 0, stream>>>(Zb, stats, N);

    // --- layer 3 (relu + BN): U-chain from BN(Zb,bnp2) -> Za ---
    wfuse_kernel<<<257, 256, 0, stream>>>(stats, g2, be2, W3, b3, Wt, bias2, bnp2, invN);
    pull128<1><<<PB, 256, 0, stream>>>(Zb, rp, ev, bnp2, T1, N);
    pull128<0><<<PB, 256, 0, stream>>>(T1, rp, ev, nullptr, T2, N);
    pull128<0><<<PB, 256, 0, stream>>>(T2, rp, ev, nullptr, T3, N);
    gemm_mfma<2, 1><<<GB, 256, 0, stream>>>(Zb, T1, T2, T3, Wt, bias2, Za, nullptr, N);
    hipMemsetAsync(stats, 0, STB, stream);
    bnstats_kernel<<<512, 256, 0, stream>>>(Za, stats, N);

    // --- layer 4 (no act/BN): U-chain from BN(Za,bnp3) -> Zf (fp32) ---
    wfuse_kernel<<<257, 256, 0, stream>>>(stats, g3, be3, W4, b4, Wt, bias2, bnp3, invN);
    pull128<1><<<PB, 256, 0, stream>>>(Za, rp, ev, bnp3, T1, N);
    pull128<0><<<PB, 256, 0, stream>>>(T1, rp, ev, nullptr, T2, N);
    pull128<0><<<PB, 256, 0, stream>>>(T2, rp, ev, nullptr, T3, N);
    gemm_mfma<0, 0><<<GB, 256, 0, stream>>>(Za, T1, T2, T3, Wt, bias2, nullptr, Zf, N);

    // --- normalize + project ---
    final_kernel<<<(N * 64 + 255) / 256, 256, 0, stream>>>(Zf, Wm, bm, out, N);
}